// Round 4
// baseline (10690.260 us; speedup 1.0000x reference)
//
#include <hip/hip_runtime.h>
#include <hip/hip_bf16.h>
#include <cstdint>

typedef __bf16 bf16_t;
typedef __bf16 bf16x8 __attribute__((ext_vector_type(8)));
typedef float  f32x4  __attribute__((ext_vector_type(4)));
typedef unsigned long long u64;
typedef unsigned int u32;
typedef unsigned short u16;

#define T_SEQ 512
#define NWG   64    // 16 h-cols per WG -> 64 gate rows (4 gates x 16 cols)

#define MFMA(a, b, c) __builtin_amdgcn_mfma_f32_16x16x32_bf16((a), (b), (c), 0, 0, 0)

static __device__ __forceinline__ u64 ldA8(const u64* p) {
  return __hip_atomic_load(p, __ATOMIC_RELAXED, __HIP_MEMORY_SCOPE_AGENT);
}
static __device__ __forceinline__ bf16x8 ld16(const bf16_t* p) {
  return *(const bf16x8*)p;
}

// ---------------- gather + convert: xe[t*64+b][512] = bf16(emb[x[b,t]]) ----------------
__global__ void gather_xe(const int* __restrict__ x, const float* __restrict__ emb,
                          bf16_t* __restrict__ xe) {
  const int row = blockIdx.x;            // row = t*64 + b
  const int b = row & 63, t = row >> 6;
  const int tok = x[b * 512 + t];        // x is [B][T]
  const float4* src = (const float4*)(emb + (size_t)tok * 512);
  float4 a = src[threadIdx.x * 2], c = src[threadIdx.x * 2 + 1];
  bf16x8 v;
  v[0] = (bf16_t)a.x; v[1] = (bf16_t)a.y; v[2] = (bf16_t)a.z; v[3] = (bf16_t)a.w;
  v[4] = (bf16_t)c.x; v[5] = (bf16_t)c.y; v[6] = (bf16_t)c.z; v[7] = (bf16_t)c.w;
  *(bf16x8*)(xe + (size_t)row * 512 + threadIdx.x * 8) = v;
}

// ---------------- f32 -> bf16 convert (8 elems/thread) ----------------
__global__ void cvt_f32_bf16(const float* __restrict__ s, bf16_t* __restrict__ d, int n8) {
  int i = blockIdx.x * blockDim.x + threadIdx.x;
  if (i >= n8) return;
  const float4* sp = (const float4*)s;
  float4 a = sp[2 * (size_t)i], b = sp[2 * (size_t)i + 1];
  bf16x8 v;
  v[0] = (bf16_t)a.x; v[1] = (bf16_t)a.y; v[2] = (bf16_t)a.z; v[3] = (bf16_t)a.w;
  v[4] = (bf16_t)b.x; v[5] = (bf16_t)b.y; v[6] = (bf16_t)b.z; v[7] = (bf16_t)b.w;
  *(bf16x8*)(d + 8 * (size_t)i) = v;
}

// ---------------- persistent sequential LSTM (cooperative, barrier-free waves) ----------------
// WG wg owns h-cols wg*16..+15 -> 64 gate rows (block g = gate g, row-in-block = col).
// Wave w owns batches w*16..+15. MFMA C-layout puts all 4 gates for (batch,col) in ONE
// lane's registers -> elementwise is in-register: NO LDS exchange, NO __syncthreads in loop.
// Sync: 256 per-WAVE flags; each wave stores its flag after vmcnt(0), polls all 256 (4/lane).
// h double-buffered in global bf16 [2][64][1024]; h traffic = agent-scope relaxed atomics
// (write-through stores / L2-bypass loads) => no cache-wiping fences needed.
__global__ __launch_bounds__(256, 1) void lstm_seq(
    const bf16_t* __restrict__ xe,       // [512*64][512]
    const bf16_t* __restrict__ wihb,     // [4096][512] bf16
    const float* __restrict__ whh,       // [4096][1024] f32
    const float* __restrict__ bih, const float* __restrict__ bhh,
    const float* __restrict__ wfc, const float* __restrict__ bfc,
    bf16_t* __restrict__ hb,             // [2][64][1024], pre-zeroed
    u32* __restrict__ flags,             // [256], pre-zeroed
    float* __restrict__ out) {
  __shared__ bf16_t whh_s[64][1032];     // 1032*2B = 129 x 16B (odd) -> conflict-benign
  const int tid = threadIdx.x, wg = blockIdx.x;
  const int lane = tid & 63, w = tid >> 6;

  // ---- stage W_hh slice f32 -> bf16 (one-time): local row r=gate*16+col ----
  {
    const int r = tid >> 2, sub = tid & 3;               // 64 rows x 4 chunks of 256
    const int grow = (r >> 4) * 1024 + wg * 16 + (r & 15);
    const float4* s = (const float4*)(whh + (size_t)grow * 1024 + sub * 256);
    bf16_t* d = &whh_s[r][sub * 256];
#pragma unroll 8
    for (int u = 0; u < 64; ++u) {
      float4 f = s[u];
      d[u * 4 + 0] = (bf16_t)f.x; d[u * 4 + 1] = (bf16_t)f.y;
      d[u * 4 + 2] = (bf16_t)f.z; d[u * 4 + 3] = (bf16_t)f.w;
    }
  }
  __syncthreads();   // the ONLY block-wide barrier

  const int rloc = lane & 15, kg = lane >> 4;
  const int b0 = w * 16;                 // wave's batch block
  const int col = wg * 16 + rloc;        // this lane's global h-column

  const float bI = bih[col] + bhh[col];
  const float bF = bih[1024 + col] + bhh[1024 + col];
  const float bG = bih[2048 + col] + bhh[2048 + col];
  const float bO = bih[3072 + col] + bhh[3072 + col];

  // B-fragment base pointers (fixed across t)
  const bf16_t* wB0 = wihb + ((size_t)0 * 1024 + wg * 16 + rloc) * 512 + kg * 8;
  const bf16_t* wB1 = wihb + ((size_t)1 * 1024 + wg * 16 + rloc) * 512 + kg * 8;
  const bf16_t* wB2 = wihb + ((size_t)2 * 1024 + wg * 16 + rloc) * 512 + kg * 8;
  const bf16_t* wB3 = wihb + ((size_t)3 * 1024 + wg * 16 + rloc) * 512 + kg * 8;
  const bf16_t* hB0 = &whh_s[rloc][kg * 8];
  const bf16_t* hB1 = &whh_s[16 + rloc][kg * 8];
  const bf16_t* hB2 = &whh_s[32 + rloc][kg * 8];
  const bf16_t* hB3 = &whh_s[48 + rloc][kg * 8];

  float c[4] = {0.f, 0.f, 0.f, 0.f};     // cell state: 4 batches x 1 col per lane

  for (int t = 0; t < T_SEQ; ++t) {
    f32x4 A0 = {0.f, 0.f, 0.f, 0.f}, A1 = A0, A2 = A0, A3 = A0;  // gates i,f,g,o

    // ---- xe[t] @ Wih^T : h-independent, runs in the wait shadow (B from global/L2) ----
    const bf16_t* ax = xe + ((size_t)t * 64 + b0 + rloc) * 512 + kg * 8;
#pragma unroll 4
    for (int kk = 0; kk < 16; ++kk) {
      bf16x8 a = ld16(ax + kk * 32);
      A0 = MFMA(a, ld16(wB0 + kk * 32), A0);
      A1 = MFMA(a, ld16(wB1 + kk * 32), A1);
      A2 = MFMA(a, ld16(wB2 + kk * 32), A2);
      A3 = MFMA(a, ld16(wB3 + kk * 32), A3);
    }

    // ---- wait: all 256 wave-flags >= t (monotonic; 4 flags per lane) ----
    {
      const u32 tgt = (u32)t;
#pragma unroll
      for (int q = 0; q < 4; ++q) {
        const u32* p = flags + q * 64 + lane;
        while (__hip_atomic_load(p, __ATOMIC_RELAXED, __HIP_MEMORY_SCOPE_AGENT) < tgt)
          __builtin_amdgcn_s_sleep(2);
      }
    }

    // ---- h(t) @ Whh^T : A via coherent 8B loads, B from LDS ----
    const u64* ah = (const u64*)(hb + (size_t)(t & 1) * 65536) +
                    ((size_t)(b0 + rloc) << 8) + (kg << 1);
#pragma unroll 4
    for (int kk = 0; kk < 32; ++kk) {
      union { u64 u[2]; bf16x8 v; } a;
      a.u[0] = ldA8(ah + kk * 8);
      a.u[1] = ldA8(ah + kk * 8 + 1);
      A0 = MFMA(a.v, ld16(hB0 + kk * 32), A0);
      A1 = MFMA(a.v, ld16(hB1 + kk * 32), A1);
      A2 = MFMA(a.v, ld16(hB2 + kk * 32), A2);
      A3 = MFMA(a.v, ld16(hB3 + kk * 32), A3);
    }

    // ---- in-register elementwise: lane = (4 batches b0+kg*4+r) x (col) ----
    u16* hn = (u16*)(hb + (size_t)((t + 1) & 1) * 65536) + (size_t)(b0 + kg * 4) * 1024 + col;
#pragma unroll
    for (int r = 0; r < 4; ++r) {
      const float gi = A0[r] + bI, gf = A1[r] + bF, gg = A2[r] + bG, go = A3[r] + bO;
      const float ii = 1.f / (1.f + __expf(-gi));
      const float ff = 1.f / (1.f + __expf(-gf));
      const float gv = tanhf(gg);
      const float oo = 1.f / (1.f + __expf(-go));
      c[r] = ff * c[r] + ii * gv;
      const float hv = oo * tanhf(c[r]);
      const bf16_t hvb = (bf16_t)hv;
      __hip_atomic_store(hn + (size_t)r * 1024, __builtin_bit_cast(u16, hvb),
                         __ATOMIC_RELAXED, __HIP_MEMORY_SCOPE_AGENT);
    }

    // ---- per-wave signal: own stores acked -> flag (plain store, no RMW) ----
    asm volatile("s_waitcnt vmcnt(0)" ::: "memory");
    if (lane == 0)
      __hip_atomic_store(flags + (wg << 2) + w, (u32)(t + 1),
                         __ATOMIC_RELAXED, __HIP_MEMORY_SCOPE_AGENT);
  }

  // ---- final FC + sigmoid on WG 0 (final h = hb[0]; wait everyone's step 511 done) ----
  if (wg != 0) return;
#pragma unroll
  for (int q = 0; q < 4; ++q) {
    const u32* p = flags + q * 64 + lane;
    while (__hip_atomic_load(p, __ATOMIC_RELAXED, __HIP_MEMORY_SCOPE_AGENT) < (u32)T_SEQ)
      __builtin_amdgcn_s_sleep(2);
  }
  {
    const int bth = tid >> 2, part = tid & 3;
    const u64* hp = (const u64*)(hb + (size_t)bth * 1024 + part * 256);
    const float* wp = wfc + part * 256;
    float s = 0.f;
    for (int i = 0; i < 64; ++i) {
      union { u64 u; bf16_t h[4]; } xv;
      xv.u = ldA8(hp + i);
      s += (float)xv.h[0] * wp[i * 4] + (float)xv.h[1] * wp[i * 4 + 1] +
           (float)xv.h[2] * wp[i * 4 + 2] + (float)xv.h[3] * wp[i * 4 + 3];
    }
    s += __shfl_xor(s, 1);
    s += __shfl_xor(s, 2);
    if (part == 0) out[bth] = 1.f / (1.f + __expf(-(s + bfc[0])));
  }
}

extern "C" void kernel_launch(void* const* d_in, const int* in_sizes, int n_in,
                              void* d_out, int out_size, void* d_ws, size_t ws_size,
                              hipStream_t stream) {
  const int* x = (const int*)d_in[0];
  const float* emb = (const float*)d_in[1];
  const float* wih = (const float*)d_in[2];
  const float* whh = (const float*)d_in[3];
  const float* bih = (const float*)d_in[4];
  const float* bhh = (const float*)d_in[5];
  const float* wfc = (const float*)d_in[6];
  const float* bfc = (const float*)d_in[7];
  float* out = (float*)d_out;

  char* ws = (char*)d_ws;
  bf16_t* xe = (bf16_t*)ws;                                    // 33,554,432 B
  bf16_t* wihb = (bf16_t*)(ws + 33554432);                     //  4,194,304 B
  bf16_t* hb = (bf16_t*)(ws + 33554432 + 4194304);             //    262,144 B
  u32* flags = (u32*)(ws + 33554432 + 4194304 + 262144);       //      1,024 B

  hipMemsetAsync(hb, 0, 262144 + 1024, stream);                // h(0), h(1), flags = 0
  gather_xe<<<32768, 64, 0, stream>>>(x, emb, xe);
  cvt_f32_bf16<<<1024, 256, 0, stream>>>(wih, wihb, 262144);

  void* args[] = {(void*)&xe, (void*)&wihb, (void*)&whh, (void*)&bih, (void*)&bhh,
                  (void*)&wfc, (void*)&bfc, (void*)&hb, (void*)&flags, (void*)&out};
  hipLaunchCooperativeKernel((const void*)lstm_seq, dim3(NWG), dim3(256), args, 0, stream);
}

// Round 7
// 10466.295 us; speedup vs baseline: 1.0214x; 1.0214x over previous
//
#include <hip/hip_runtime.h>
#include <hip/hip_bf16.h>
#include <cstdint>

typedef __bf16 bf16_t;
typedef __bf16 bf16x8 __attribute__((ext_vector_type(8)));
typedef float  f32x4  __attribute__((ext_vector_type(4)));
typedef unsigned long long u64;
typedef unsigned int u32;
typedef unsigned short u16;

#define T_SEQ 512
#define NWG   64    // 16 h-cols per WG -> 64 gate rows (4 gates x 16 cols)

#define MFMA(a, b, c) __builtin_amdgcn_mfma_f32_16x16x32_bf16((a), (b), (c), 0, 0, 0)

static __device__ __forceinline__ u64 ldA8(const u64* p) {
  return __hip_atomic_load(p, __ATOMIC_RELAXED, __HIP_MEMORY_SCOPE_AGENT);
}
static __device__ __forceinline__ bf16x8 ld16(const bf16_t* p) {
  return *(const bf16x8*)p;
}

// ---------------- gather + convert: xe[t*64+b][512] = bf16(emb[x[b,t]]) ----------------
__global__ void gather_xe(const int* __restrict__ x, const float* __restrict__ emb,
                          bf16_t* __restrict__ xe) {
  const int row = blockIdx.x;            // row = t*64 + b
  const int b = row & 63, t = row >> 6;
  const int tok = x[b * 512 + t];        // x is [B][T]
  const float4* src = (const float4*)(emb + (size_t)tok * 512);
  float4 a = src[threadIdx.x * 2], c = src[threadIdx.x * 2 + 1];
  bf16x8 v;
  v[0] = (bf16_t)a.x; v[1] = (bf16_t)a.y; v[2] = (bf16_t)a.z; v[3] = (bf16_t)a.w;
  v[4] = (bf16_t)c.x; v[5] = (bf16_t)c.y; v[6] = (bf16_t)c.z; v[7] = (bf16_t)c.w;
  *(bf16x8*)(xe + (size_t)row * 512 + threadIdx.x * 8) = v;
}

// ---------------- f32 -> bf16 convert (8 elems/thread) ----------------
__global__ void cvt_f32_bf16(const float* __restrict__ s, bf16_t* __restrict__ d, int n8) {
  int i = blockIdx.x * blockDim.x + threadIdx.x;
  if (i >= n8) return;
  const float4* sp = (const float4*)s;
  float4 a = sp[2 * (size_t)i], b = sp[2 * (size_t)i + 1];
  bf16x8 v;
  v[0] = (bf16_t)a.x; v[1] = (bf16_t)a.y; v[2] = (bf16_t)a.z; v[3] = (bf16_t)a.w;
  v[4] = (bf16_t)b.x; v[5] = (bf16_t)b.y; v[6] = (bf16_t)b.z; v[7] = (bf16_t)b.w;
  *(bf16x8*)(d + 8 * (size_t)i) = v;
}

// ---------------- persistent sequential LSTM (cooperative) ----------------
// Data path: EXACT R4 (verified absmax 0.0). WG wg owns h-cols wg*16..+15 -> 64 gate
// rows; wave w owns batches w*16..+15; in-register elementwise via MFMA C-layout.
// Sync per step (R3-proven mechanisms only, no RMW):
//   producer: per-wave vmcnt(0) -> __syncthreads -> tid0 plain store flags[wg]=t+1
//   consumer: wave0 does ONE coalesced load of all 64 flags + __all; then
//             __syncthreads fanout (hard codegen barrier -> no h-load hoisting hole).
__global__ __launch_bounds__(256, 1) void lstm_seq(
    const bf16_t* __restrict__ xe,       // [512*64][512]
    const bf16_t* __restrict__ wihb,     // [4096][512] bf16
    const float* __restrict__ whh,       // [4096][1024] f32
    const float* __restrict__ bih, const float* __restrict__ bhh,
    const float* __restrict__ wfc, const float* __restrict__ bfc,
    bf16_t* __restrict__ hb,             // [2][64][1024], pre-zeroed
    u32* __restrict__ flags,             // [64], pre-zeroed
    float* __restrict__ out) {
  __shared__ bf16_t whh_s[64][1032];     // 132 KB; odd 16B row stride -> benign conflicts
  const int tid = threadIdx.x, wg = blockIdx.x;
  const int lane = tid & 63, w = tid >> 6;

  // ---- stage W_hh slice f32 -> bf16 (one-time): local row r = gate*16 + col ----
  {
    const int r = tid >> 2, sub = tid & 3;               // 64 rows x 4 chunks of 256
    const int grow = (r >> 4) * 1024 + wg * 16 + (r & 15);
    const float4* s = (const float4*)(whh + (size_t)grow * 1024 + sub * 256);
    bf16_t* d = &whh_s[r][sub * 256];
#pragma unroll 8
    for (int u = 0; u < 64; ++u) {
      float4 f = s[u];
      d[u * 4 + 0] = (bf16_t)f.x; d[u * 4 + 1] = (bf16_t)f.y;
      d[u * 4 + 2] = (bf16_t)f.z; d[u * 4 + 3] = (bf16_t)f.w;
    }
  }
  __syncthreads();

  const int rloc = lane & 15, kg = lane >> 4;
  const int b0 = w * 16;                 // wave's batch block
  const int col = wg * 16 + rloc;        // this lane's global h-column

  const float bI = bih[col] + bhh[col];
  const float bF = bih[1024 + col] + bhh[1024 + col];
  const float bG = bih[2048 + col] + bhh[2048 + col];
  const float bO = bih[3072 + col] + bhh[3072 + col];

  const bf16_t* wB0 = wihb + ((size_t)0 * 1024 + wg * 16 + rloc) * 512 + kg * 8;
  const bf16_t* wB1 = wihb + ((size_t)1 * 1024 + wg * 16 + rloc) * 512 + kg * 8;
  const bf16_t* wB2 = wihb + ((size_t)2 * 1024 + wg * 16 + rloc) * 512 + kg * 8;
  const bf16_t* wB3 = wihb + ((size_t)3 * 1024 + wg * 16 + rloc) * 512 + kg * 8;
  const bf16_t* hB0 = &whh_s[rloc][kg * 8];
  const bf16_t* hB1 = &whh_s[16 + rloc][kg * 8];
  const bf16_t* hB2 = &whh_s[32 + rloc][kg * 8];
  const bf16_t* hB3 = &whh_s[48 + rloc][kg * 8];

  float c[4] = {0.f, 0.f, 0.f, 0.f};

  for (int t = 0; t < T_SEQ; ++t) {
    f32x4 A0 = {0.f, 0.f, 0.f, 0.f}, A1 = A0, A2 = A0, A3 = A0;  // i,f,g,o

    // ---- xe[t] @ Wih^T : h-independent, runs in the wait shadow ----
    const bf16_t* ax = xe + ((size_t)t * 64 + b0 + rloc) * 512 + kg * 8;
#pragma unroll 4
    for (int kk = 0; kk < 16; ++kk) {
      bf16x8 a = ld16(ax + kk * 32);
      A0 = MFMA(a, ld16(wB0 + kk * 32), A0);
      A1 = MFMA(a, ld16(wB1 + kk * 32), A1);
      A2 = MFMA(a, ld16(wB2 + kk * 32), A2);
      A3 = MFMA(a, ld16(wB3 + kk * 32), A3);
    }

    // ---- wait for h(t): wave0 coalesced poll + __all, then __syncthreads fanout ----
    if (t) {
      if (w == 0) {
        const u32 tgt = (u32)t;
        u32 v = __hip_atomic_load(flags + lane, __ATOMIC_RELAXED, __HIP_MEMORY_SCOPE_AGENT);
        while (!__all(v >= tgt)) {
          __builtin_amdgcn_s_sleep(2);
          v = __hip_atomic_load(flags + lane, __ATOMIC_RELAXED, __HIP_MEMORY_SCOPE_AGENT);
        }
      }
      __syncthreads();
    }

    // ---- h(t) @ Whh^T : A via coherent 8B loads, B from LDS ----
    // h row = 1024 bf16 = 2048 B = 256 u64 -> batch-row stride <<8 in u64 units
    const u64* ah = (const u64*)(hb + (size_t)(t & 1) * 65536) +
                    ((size_t)(b0 + rloc) << 8) + (kg << 1);
#pragma unroll 4
    for (int kk = 0; kk < 32; ++kk) {
      union { u64 u[2]; bf16x8 v; } a;
      a.u[0] = ldA8(ah + kk * 8);
      a.u[1] = ldA8(ah + kk * 8 + 1);
      A0 = MFMA(a.v, ld16(hB0 + kk * 32), A0);
      A1 = MFMA(a.v, ld16(hB1 + kk * 32), A1);
      A2 = MFMA(a.v, ld16(hB2 + kk * 32), A2);
      A3 = MFMA(a.v, ld16(hB3 + kk * 32), A3);
    }

    // ---- in-register elementwise: lane = (4 batches b0+kg*4+r) x (col) ----
    u16* hn = (u16*)(hb + (size_t)((t + 1) & 1) * 65536) + (size_t)(b0 + kg * 4) * 1024 + col;
#pragma unroll
    for (int r = 0; r < 4; ++r) {
      const float gi = A0[r] + bI, gf = A1[r] + bF, gg = A2[r] + bG, go = A3[r] + bO;
      const float ii = 1.f / (1.f + __expf(-gi));
      const float ff = 1.f / (1.f + __expf(-gf));
      const float gv = tanhf(gg);
      const float oo = 1.f / (1.f + __expf(-go));
      c[r] = ff * c[r] + ii * gv;
      const float hv = oo * tanhf(c[r]);
      const bf16_t hvb = (bf16_t)hv;
      __hip_atomic_store(hn + (size_t)r * 1024, __builtin_bit_cast(u16, hvb),
                         __ATOMIC_RELAXED, __HIP_MEMORY_SCOPE_AGENT);
    }

    // ---- producer: all waves drained -> barrier -> tid0 plain store flags[wg]=t+1 ----
    asm volatile("s_waitcnt vmcnt(0)" ::: "memory");
    __syncthreads();
    if (tid == 0)
      __hip_atomic_store(flags + wg, (u32)(t + 1), __ATOMIC_RELAXED, __HIP_MEMORY_SCOPE_AGENT);
  }

  // ---- final FC + sigmoid on WG 0 (final h = hb[0] after 512 steps) ----
  if (wg != 0) return;
  if (w == 0) {
    u32 v = __hip_atomic_load(flags + lane, __ATOMIC_RELAXED, __HIP_MEMORY_SCOPE_AGENT);
    while (!__all(v >= (u32)T_SEQ)) {
      __builtin_amdgcn_s_sleep(2);
      v = __hip_atomic_load(flags + lane, __ATOMIC_RELAXED, __HIP_MEMORY_SCOPE_AGENT);
    }
  }
  __syncthreads();
  {
    const int bth = tid >> 2, part = tid & 3;
    const u64* hp = (const u64*)(hb + (size_t)bth * 1024 + part * 256);
    const float* wp = wfc + part * 256;
    float s = 0.f;
    for (int i = 0; i < 64; ++i) {
      union { u64 u; bf16_t h[4]; } xv;
      xv.u = ldA8(hp + i);
      s += (float)xv.h[0] * wp[i * 4] + (float)xv.h[1] * wp[i * 4 + 1] +
           (float)xv.h[2] * wp[i * 4 + 2] + (float)xv.h[3] * wp[i * 4 + 3];
    }
    s += __shfl_xor(s, 1);
    s += __shfl_xor(s, 2);
    if (part == 0) out[bth] = 1.f / (1.f + __expf(-(s + bfc[0])));
  }
}

extern "C" void kernel_launch(void* const* d_in, const int* in_sizes, int n_in,
                              void* d_out, int out_size, void* d_ws, size_t ws_size,
                              hipStream_t stream) {
  const int* x = (const int*)d_in[0];
  const float* emb = (const float*)d_in[1];
  const float* wih = (const float*)d_in[2];
  const float* whh = (const float*)d_in[3];
  const float* bih = (const float*)d_in[4];
  const float* bhh = (const float*)d_in[5];
  const float* wfc = (const float*)d_in[6];
  const float* bfc = (const float*)d_in[7];
  float* out = (float*)d_out;

  char* ws = (char*)d_ws;
  bf16_t* xe = (bf16_t*)ws;                                    // 33,554,432 B
  bf16_t* wihb = (bf16_t*)(ws + 33554432);                     //  4,194,304 B
  bf16_t* hb = (bf16_t*)(ws + 33554432 + 4194304);             //    262,144 B
  u32* flags = (u32*)(ws + 33554432 + 4194304 + 262144);       //        256 B

  hipMemsetAsync(hb, 0, 262144 + 1024, stream);                // h buffers + flags = 0
  gather_xe<<<32768, 64, 0, stream>>>(x, emb, xe);
  cvt_f32_bf16<<<1024, 256, 0, stream>>>(wih, wihb, 262144);

  void* args[] = {(void*)&xe, (void*)&wihb, (void*)&whh, (void*)&bih, (void*)&bhh,
                  (void*)&wfc, (void*)&bfc, (void*)&hb, (void*)&flags, (void*)&out};
  hipLaunchCooperativeKernel((const void*)lstm_seq, dim3(NWG), dim3(256), args, 0, stream);
}

// Round 8
// 4732.919 us; speedup vs baseline: 2.2587x; 2.2114x over previous
//
#include <hip/hip_runtime.h>
#include <hip/hip_bf16.h>
#include <cstdint>

typedef __bf16 bf16_t;
typedef __bf16 bf16x8 __attribute__((ext_vector_type(8)));
typedef float  f32x4  __attribute__((ext_vector_type(4)));
typedef unsigned long long u64;
typedef unsigned int u32;
typedef unsigned short u16;

#define T_SEQ 512
#define NWG   64    // 16 h-cols per WG -> 64 gate rows (4 gates x 16 cols)
#define HROT  64    // h-buffer rotation depth (staleness-by-construction window)

#define MFMA(a, b, c) __builtin_amdgcn_mfma_f32_16x16x32_bf16((a), (b), (c), 0, 0, 0)

static __device__ __forceinline__ u64 ldA8(const u64* p) {
  return __hip_atomic_load(p, __ATOMIC_RELAXED, __HIP_MEMORY_SCOPE_AGENT);
}
static __device__ __forceinline__ bf16x8 ld16(const bf16_t* p) {
  return *(const bf16x8*)p;
}

// ---------------- gather + convert: xe[t*64+b][512] = bf16(emb[x[b,t]]) ----------------
__global__ void gather_xe(const int* __restrict__ x, const float* __restrict__ emb,
                          bf16_t* __restrict__ xe) {
  const int row = blockIdx.x;            // row = t*64 + b
  const int b = row & 63, t = row >> 6;
  const int tok = x[b * 512 + t];        // x is [B][T]
  const float4* src = (const float4*)(emb + (size_t)tok * 512);
  float4 a = src[threadIdx.x * 2], c = src[threadIdx.x * 2 + 1];
  bf16x8 v;
  v[0] = (bf16_t)a.x; v[1] = (bf16_t)a.y; v[2] = (bf16_t)a.z; v[3] = (bf16_t)a.w;
  v[4] = (bf16_t)c.x; v[5] = (bf16_t)c.y; v[6] = (bf16_t)c.z; v[7] = (bf16_t)c.w;
  *(bf16x8*)(xe + (size_t)row * 512 + threadIdx.x * 8) = v;
}

// ---------------- f32 -> bf16 convert (8 elems/thread) ----------------
__global__ void cvt_f32_bf16(const float* __restrict__ s, bf16_t* __restrict__ d, int n8) {
  int i = blockIdx.x * blockDim.x + threadIdx.x;
  if (i >= n8) return;
  const float4* sp = (const float4*)s;
  float4 a = sp[2 * (size_t)i], b = sp[2 * (size_t)i + 1];
  bf16x8 v;
  v[0] = (bf16_t)a.x; v[1] = (bf16_t)a.y; v[2] = (bf16_t)a.z; v[3] = (bf16_t)a.w;
  v[4] = (bf16_t)b.x; v[5] = (bf16_t)b.y; v[6] = (bf16_t)b.z; v[7] = (bf16_t)b.w;
  *(bf16x8*)(d + 8 * (size_t)i) = v;
}

// ---------------- persistent sequential LSTM (cooperative, 8 waves, K-split) ----------------
// WG wg owns h-cols wg*16..+15 -> 64 gate rows. 8 waves: wl=w&3 owns batches wl*16..+15,
// kh=w>>2 owns K-half (h: kh*512..+512, xe: kh*256..+256). LDS reduce merges halves.
// h rotates through HROT global buffers: consumer reads are PLAIN wide nt loads (virgin
// addresses within the rotation window -> never L2-stale); producer stores stay agent-scope
// write-through. Sync: R7-proven per-WG flags, wave0 coalesced poll + __all, barrier fanout.
__global__ __launch_bounds__(512, 1) void lstm_seq(
    const bf16_t* __restrict__ xe,       // [512*64][512]
    const bf16_t* __restrict__ wihb,     // [4096][512] bf16
    const float* __restrict__ whh,       // [4096][1024] f32
    const float* __restrict__ bih, const float* __restrict__ bhh,
    const float* __restrict__ wfc, const float* __restrict__ bfc,
    bf16_t* __restrict__ hb,             // [HROT][64][1024]; buffer 0 pre-zeroed
    u32* __restrict__ flags,             // [64], pre-zeroed
    float* __restrict__ out) {
  __shared__ bf16_t whh_s[64][1032];     // 132 KB
  __shared__ f32x4 red_s[4][4][64];      //  16 KB, lane-contiguous -> conflict-free
  const int tid = threadIdx.x, wg = blockIdx.x;
  const int lane = tid & 63, w = tid >> 6;
  const int wl = w & 3, kh = w >> 2;

  // ---- stage W_hh slice f32 -> bf16 (one-time): local row r = gate*16 + col ----
  {
    const int r = tid >> 3, sub = tid & 7;               // 64 rows x 8 chunks of 128 f32
    const int grow = (r >> 4) * 1024 + wg * 16 + (r & 15);
    const float4* s = (const float4*)(whh + (size_t)grow * 1024 + sub * 128);
    bf16_t* d = &whh_s[r][sub * 128];
#pragma unroll 8
    for (int u = 0; u < 32; ++u) {
      float4 f = s[u];
      d[u * 4 + 0] = (bf16_t)f.x; d[u * 4 + 1] = (bf16_t)f.y;
      d[u * 4 + 2] = (bf16_t)f.z; d[u * 4 + 3] = (bf16_t)f.w;
    }
  }
  __syncthreads();

  const int rloc = lane & 15, kg = lane >> 4;
  const int b0 = wl * 16;                // wave's batch block
  const int col = wg * 16 + rloc;        // this lane's global h-column
  const int kx0 = kh * 256;              // xe K-half base
  const int kh0 = kh * 512;              // h  K-half base

  const float bI = bih[col] + bhh[col];
  const float bF = bih[1024 + col] + bhh[1024 + col];
  const float bG = bih[2048 + col] + bhh[2048 + col];
  const float bO = bih[3072 + col] + bhh[3072 + col];

  const bf16_t* wB0 = wihb + ((size_t)(0 * 1024 + wg * 16 + rloc)) * 512 + kx0 + kg * 8;
  const bf16_t* wB1 = wihb + ((size_t)(1 * 1024 + wg * 16 + rloc)) * 512 + kx0 + kg * 8;
  const bf16_t* wB2 = wihb + ((size_t)(2 * 1024 + wg * 16 + rloc)) * 512 + kx0 + kg * 8;
  const bf16_t* wB3 = wihb + ((size_t)(3 * 1024 + wg * 16 + rloc)) * 512 + kx0 + kg * 8;
  const bf16_t* hB0 = &whh_s[ 0 + rloc][kh0 + kg * 8];
  const bf16_t* hB1 = &whh_s[16 + rloc][kh0 + kg * 8];
  const bf16_t* hB2 = &whh_s[32 + rloc][kh0 + kg * 8];
  const bf16_t* hB3 = &whh_s[48 + rloc][kh0 + kg * 8];

  float c[4] = {0.f, 0.f, 0.f, 0.f};

  for (int t = 0; t < T_SEQ; ++t) {
    f32x4 A0 = {0.f, 0.f, 0.f, 0.f}, A1 = A0, A2 = A0, A3 = A0;  // i,f,g,o

    // ---- xe[t] @ Wih^T (own K-quarter-half): h-independent, runs in the wait shadow ----
    const bf16_t* ax = xe + ((size_t)t * 64 + b0 + rloc) * 512 + kx0 + kg * 8;
#pragma unroll
    for (int kk = 0; kk < 8; ++kk) {
      bf16x8 a = ld16(ax + kk * 32);
      A0 = MFMA(a, ld16(wB0 + kk * 32), A0);
      A1 = MFMA(a, ld16(wB1 + kk * 32), A1);
      A2 = MFMA(a, ld16(wB2 + kk * 32), A2);
      A3 = MFMA(a, ld16(wB3 + kk * 32), A3);
    }

    // ---- wait for h(t): wave0 coalesced poll + __all, then barrier fanout ----
    if (t) {
      if (w == 0) {
        const u32 tgt = (u32)t;
        u32 v = __hip_atomic_load(flags + lane, __ATOMIC_RELAXED, __HIP_MEMORY_SCOPE_AGENT);
        while (!__all(v >= tgt)) {
          __builtin_amdgcn_s_sleep(2);
          v = __hip_atomic_load(flags + lane, __ATOMIC_RELAXED, __HIP_MEMORY_SCOPE_AGENT);
        }
      }
      __syncthreads();
      asm volatile("" ::: "memory");   // pin h loads below the barrier
    }

    // ---- h(t) @ Whh^T (own K-half): PLAIN wide nt loads (rotated buffer => never stale) ----
    const bf16_t* ah = hb + (size_t)(t & (HROT - 1)) * 65536 +
                       (size_t)(b0 + rloc) * 1024 + kh0 + kg * 8;
#pragma unroll
    for (int kk = 0; kk < 16; ++kk) {
      bf16x8 a = __builtin_nontemporal_load((const bf16x8*)(ah + kk * 32));
      A0 = MFMA(a, ld16(hB0 + kk * 32), A0);
      A1 = MFMA(a, ld16(hB1 + kk * 32), A1);
      A2 = MFMA(a, ld16(hB2 + kk * 32), A2);
      A3 = MFMA(a, ld16(hB3 + kk * 32), A3);
    }

    // ---- K-half reduce via LDS, then in-register elementwise on lower waves ----
    if (kh == 1) {
      red_s[wl][0][lane] = A0; red_s[wl][1][lane] = A1;
      red_s[wl][2][lane] = A2; red_s[wl][3][lane] = A3;
    }
    __syncthreads();
    if (kh == 0) {
      A0 += red_s[wl][0][lane]; A1 += red_s[wl][1][lane];
      A2 += red_s[wl][2][lane]; A3 += red_s[wl][3][lane];
      u16* hn = (u16*)(hb + (size_t)((t + 1) & (HROT - 1)) * 65536) +
                (size_t)(b0 + kg * 4) * 1024 + col;
#pragma unroll
      for (int r = 0; r < 4; ++r) {
        const float gi = A0[r] + bI, gf = A1[r] + bF, gg = A2[r] + bG, go = A3[r] + bO;
        const float ii = 1.f / (1.f + __expf(-gi));
        const float ff = 1.f / (1.f + __expf(-gf));
        const float gv = tanhf(gg);
        const float oo = 1.f / (1.f + __expf(-go));
        c[r] = ff * c[r] + ii * gv;
        const float hv = oo * tanhf(c[r]);
        const bf16_t hvb = (bf16_t)hv;
        __hip_atomic_store(hn + (size_t)r * 1024, __builtin_bit_cast(u16, hvb),
                           __ATOMIC_RELAXED, __HIP_MEMORY_SCOPE_AGENT);
      }
      asm volatile("s_waitcnt vmcnt(0)" ::: "memory");   // own h-stores globally visible
    }
    __syncthreads();   // all lower waves drained + red_s consumed
    if (tid == 0)
      __hip_atomic_store(flags + wg, (u32)(t + 1), __ATOMIC_RELAXED, __HIP_MEMORY_SCOPE_AGENT);
  }

  // ---- final FC + sigmoid on WG 0 (final h = hb[(T_SEQ)&(HROT-1)] = hb[0]) ----
  if (wg != 0) return;
  if (w == 0) {
    u32 v = __hip_atomic_load(flags + lane, __ATOMIC_RELAXED, __HIP_MEMORY_SCOPE_AGENT);
    while (!__all(v >= (u32)T_SEQ)) {
      __builtin_amdgcn_s_sleep(2);
      v = __hip_atomic_load(flags + lane, __ATOMIC_RELAXED, __HIP_MEMORY_SCOPE_AGENT);
    }
  }
  __syncthreads();
  if (tid < 256) {
    const int bth = tid >> 2, part = tid & 3;
    const u64* hp = (const u64*)(hb + (size_t)bth * 1024 + part * 256);
    const float* wp = wfc + part * 256;
    float s = 0.f;
    for (int i = 0; i < 64; ++i) {
      union { u64 u; bf16_t h[4]; } xv;
      xv.u = ldA8(hp + i);
      s += (float)xv.h[0] * wp[i * 4] + (float)xv.h[1] * wp[i * 4 + 1] +
           (float)xv.h[2] * wp[i * 4 + 2] + (float)xv.h[3] * wp[i * 4 + 3];
    }
    s += __shfl_xor(s, 1);
    s += __shfl_xor(s, 2);
    if (part == 0) out[bth] = 1.f / (1.f + __expf(-(s + bfc[0])));
  }
}

extern "C" void kernel_launch(void* const* d_in, const int* in_sizes, int n_in,
                              void* d_out, int out_size, void* d_ws, size_t ws_size,
                              hipStream_t stream) {
  const int* x = (const int*)d_in[0];
  const float* emb = (const float*)d_in[1];
  const float* wih = (const float*)d_in[2];
  const float* whh = (const float*)d_in[3];
  const float* bih = (const float*)d_in[4];
  const float* bhh = (const float*)d_in[5];
  const float* wfc = (const float*)d_in[6];
  const float* bfc = (const float*)d_in[7];
  float* out = (float*)d_out;

  char* ws = (char*)d_ws;
  bf16_t* xe = (bf16_t*)ws;                                    // 33,554,432 B
  bf16_t* wihb = (bf16_t*)(ws + 33554432);                     //  4,194,304 B
  bf16_t* hb = (bf16_t*)(ws + 33554432 + 4194304);             //  8,388,608 B (64 x 128 KB)
  u32* flags = (u32*)(ws + 33554432 + 4194304 + 8388608);      //        256 B

  hipMemsetAsync(hb, 0, 131072, stream);                       // h buffer 0 = 0
  hipMemsetAsync(flags, 0, 256, stream);                       // flags = 0
  gather_xe<<<32768, 64, 0, stream>>>(x, emb, xe);
  cvt_f32_bf16<<<1024, 256, 0, stream>>>(wih, wihb, 262144);

  void* args[] = {(void*)&xe, (void*)&wihb, (void*)&whh, (void*)&bih, (void*)&bhh,
                  (void*)&wfc, (void*)&bfc, (void*)&hb, (void*)&flags, (void*)&out};
  hipLaunchCooperativeKernel((const void*)lstm_seq, dim3(NWG), dim3(512), args, 0, stream);
}

// Round 9
// 3380.293 us; speedup vs baseline: 3.1625x; 1.4002x over previous
//
#include <hip/hip_runtime.h>
#include <hip/hip_bf16.h>
#include <cstdint>

typedef __bf16 bf16_t;
typedef __bf16 bf16x8 __attribute__((ext_vector_type(8)));
typedef float  f32x4  __attribute__((ext_vector_type(4)));
typedef unsigned long long u64;
typedef unsigned int u32;
typedef unsigned short u16;

#define T_SEQ 512
#define HROT  64    // h-buffer rotation depth
#define NCOLG 64    // column groups (16 cols each) per clique
#define NCLQ  4     // independent batch cliques (16 batches each)

#define MFMA(a, b, c) __builtin_amdgcn_mfma_f32_16x16x32_bf16((a), (b), (c), 0, 0, 0)

static __device__ __forceinline__ u64 ldA8(const u64* p) {
  return __hip_atomic_load(p, __ATOMIC_RELAXED, __HIP_MEMORY_SCOPE_AGENT);
}
static __device__ __forceinline__ bf16x8 ld16(const bf16_t* p) {
  return *(const bf16x8*)p;
}

// ---------------- gather + convert: xe[t*64+b][512] = bf16(emb[x[b,t]]) ----------------
__global__ void gather_xe(const int* __restrict__ x, const float* __restrict__ emb,
                          bf16_t* __restrict__ xe) {
  const int row = blockIdx.x;            // row = t*64 + b
  const int b = row & 63, t = row >> 6;
  const int tok = x[b * 512 + t];        // x is [B][T]
  const float4* src = (const float4*)(emb + (size_t)tok * 512);
  float4 a = src[threadIdx.x * 2], c = src[threadIdx.x * 2 + 1];
  bf16x8 v;
  v[0] = (bf16_t)a.x; v[1] = (bf16_t)a.y; v[2] = (bf16_t)a.z; v[3] = (bf16_t)a.w;
  v[4] = (bf16_t)c.x; v[5] = (bf16_t)c.y; v[6] = (bf16_t)c.z; v[7] = (bf16_t)c.w;
  *(bf16x8*)(xe + (size_t)row * 512 + threadIdx.x * 8) = v;
}

// ---------------- f32 -> bf16 convert (8 elems/thread) ----------------
__global__ void cvt_f32_bf16(const float* __restrict__ s, bf16_t* __restrict__ d, int n8) {
  int i = blockIdx.x * blockDim.x + threadIdx.x;
  if (i >= n8) return;
  const float4* sp = (const float4*)s;
  float4 a = sp[2 * (size_t)i], b = sp[2 * (size_t)i + 1];
  bf16x8 v;
  v[0] = (bf16_t)a.x; v[1] = (bf16_t)a.y; v[2] = (bf16_t)a.z; v[3] = (bf16_t)a.w;
  v[4] = (bf16_t)b.x; v[5] = (bf16_t)b.y; v[6] = (bf16_t)b.z; v[7] = (bf16_t)b.w;
  *(bf16x8*)(d + 8 * (size_t)i) = v;
}

// ---------------- persistent sequential LSTM: 4 independent batch cliques ----------------
// Block (clq, colg): clq owns batches clq*16..+15 (recurrence-independent of other cliques),
// colg owns h-cols colg*16..+15 -> 64 gate rows in LDS. 8 waves K-split (h:128, xe:64 each);
// waves 1-7 dump partials to LDS; wave0 reduces + elementwise + h-store + signal; wave1 is
// the dedicated flag poller. Sync per clique: 64 per-WG plain-store flags, coalesced __all
// poll, barrier fanout (R7/R8-proven). h rotates through HROT buffers (plain nt loads fresh
// by construction); h stores agent-scope write-through; no fences anywhere.
__global__ __launch_bounds__(512, 1) void lstm_seq(
    const bf16_t* __restrict__ xe,       // [512*64][512]
    const bf16_t* __restrict__ wihb,     // [4096][512] bf16
    const float* __restrict__ whh,       // [4096][1024] f32
    const float* __restrict__ bih, const float* __restrict__ bhh,
    const float* __restrict__ wfc, const float* __restrict__ bfc,
    bf16_t* __restrict__ hb,             // [HROT][64][1024]; buffer 0 pre-zeroed
    u32* __restrict__ flags,             // [NCLQ][64], pre-zeroed
    float* __restrict__ out) {
  __shared__ bf16_t whh_s[64][1032];     // 132,096 B
  __shared__ f32x4 red_s[7][4][64];      //  28,672 B  (total 160,768 <= 163,840)
  const int tid = threadIdx.x, bid = blockIdx.x;
  const int lane = tid & 63, w = tid >> 6;
  const int clq = (bid & 7) >> 1;                     // XCD-pair clique (locality heuristic)
  const int colg = ((bid >> 3) << 1) | (bid & 1);     // 0..63
  u32* flg = flags + clq * 64;

  // ---- stage W_hh slice f32 -> bf16 (one-time): local row r = gate*16 + c ----
  {
    const int r = tid >> 3, sub = tid & 7;            // 64 rows x 8 chunks of 128 f32
    const int grow = (r >> 4) * 1024 + colg * 16 + (r & 15);
    const float4* s = (const float4*)(whh + (size_t)grow * 1024 + sub * 128);
    bf16_t* d = &whh_s[r][sub * 128];
#pragma unroll 8
    for (int u = 0; u < 32; ++u) {
      float4 f = s[u];
      d[u * 4 + 0] = (bf16_t)f.x; d[u * 4 + 1] = (bf16_t)f.y;
      d[u * 4 + 2] = (bf16_t)f.z; d[u * 4 + 3] = (bf16_t)f.w;
    }
  }
  __syncthreads();

  const int rloc = lane & 15, kg = lane >> 4;
  const int col = colg * 16 + rloc;      // B-row / store column
  const int brow = clq * 16 + rloc;      // A-row (global batch)

  const float bI = bih[col] + bhh[col];
  const float bF = bih[1024 + col] + bhh[1024 + col];
  const float bG = bih[2048 + col] + bhh[2048 + col];
  const float bO = bih[3072 + col] + bhh[3072 + col];

  // B-frag bases: this wave's K-slice (xe: w*64, h: w*128)
  const bf16_t* wB0 = wihb + ((size_t)(0 * 1024 + col)) * 512 + w * 64 + kg * 8;
  const bf16_t* wB1 = wihb + ((size_t)(1 * 1024 + col)) * 512 + w * 64 + kg * 8;
  const bf16_t* wB2 = wihb + ((size_t)(2 * 1024 + col)) * 512 + w * 64 + kg * 8;
  const bf16_t* wB3 = wihb + ((size_t)(3 * 1024 + col)) * 512 + w * 64 + kg * 8;
  const bf16_t* hB0 = &whh_s[ 0 + rloc][w * 128 + kg * 8];
  const bf16_t* hB1 = &whh_s[16 + rloc][w * 128 + kg * 8];
  const bf16_t* hB2 = &whh_s[32 + rloc][w * 128 + kg * 8];
  const bf16_t* hB3 = &whh_s[48 + rloc][w * 128 + kg * 8];

  float cs[4] = {0.f, 0.f, 0.f, 0.f};   // cell state (wave0 lanes only)

  for (int t = 0; t < T_SEQ; ++t) {
    f32x4 A0 = {0.f, 0.f, 0.f, 0.f}, A1 = A0, A2 = A0, A3 = A0;  // i,f,g,o partials

    // ---- xe[t] @ Wih^T (own K-slice of 64): waves != 1 run it pre-wait ----
    const bf16_t* ax = xe + ((size_t)t * 64 + brow) * 512 + w * 64 + kg * 8;
#define XE_PART                                            \
    _Pragma("unroll")                                      \
    for (int kk = 0; kk < 2; ++kk) {                       \
      bf16x8 a = ld16(ax + kk * 32);                       \
      A0 = MFMA(a, ld16(wB0 + kk * 32), A0);               \
      A1 = MFMA(a, ld16(wB1 + kk * 32), A1);               \
      A2 = MFMA(a, ld16(wB2 + kk * 32), A2);               \
      A3 = MFMA(a, ld16(wB3 + kk * 32), A3);               \
    }
    if (w != 1) { XE_PART }

    // ---- wait for h(t): wave1 coalesced poll of own clique's 64 flags + __all ----
    if (t) {
      if (w == 1) {
        const u32 tgt = (u32)t;
        u32 v = __hip_atomic_load(flg + lane, __ATOMIC_RELAXED, __HIP_MEMORY_SCOPE_AGENT);
        while (!__all(v >= tgt)) {
          __builtin_amdgcn_s_sleep(1);
          v = __hip_atomic_load(flg + lane, __ATOMIC_RELAXED, __HIP_MEMORY_SCOPE_AGENT);
        }
      }
      __syncthreads();
      asm volatile("" ::: "memory");   // pin h loads below the barrier
    }
    if (w == 1) { XE_PART }
#undef XE_PART

    // ---- h(t) @ Whh^T (own K-slice of 128): plain nt loads, rotated buffer ----
    const bf16_t* ah = hb + (size_t)(t & (HROT - 1)) * 65536 +
                       (size_t)brow * 1024 + w * 128 + kg * 8;
#pragma unroll
    for (int kk = 0; kk < 4; ++kk) {
      bf16x8 a = __builtin_nontemporal_load((const bf16x8*)(ah + kk * 32));
      A0 = MFMA(a, ld16(hB0 + kk * 32), A0);
      A1 = MFMA(a, ld16(hB1 + kk * 32), A1);
      A2 = MFMA(a, ld16(hB2 + kk * 32), A2);
      A3 = MFMA(a, ld16(hB3 + kk * 32), A3);
    }

    // ---- K-reduce: waves 1-7 dump partials; wave0 sums after barrier ----
    if (w) {
      red_s[w - 1][0][lane] = A0; red_s[w - 1][1][lane] = A1;
      red_s[w - 1][2][lane] = A2; red_s[w - 1][3][lane] = A3;
    }
    __syncthreads();                     // #1: partials visible
    if (w == 0) {
#pragma unroll
      for (int q = 0; q < 7; ++q) {
        A0 += red_s[q][0][lane]; A1 += red_s[q][1][lane];
        A2 += red_s[q][2][lane]; A3 += red_s[q][3][lane];
      }
    }
    __syncthreads();                     // #2: red_s free for next step

    // ---- wave0: elementwise + h-store + drain + signal (others run ahead) ----
    if (w == 0) {
      u16* hn = (u16*)(hb + (size_t)((t + 1) & (HROT - 1)) * 65536) +
                (size_t)(clq * 16 + kg * 4) * 1024 + col;
#pragma unroll
      for (int r = 0; r < 4; ++r) {
        const float gi = A0[r] + bI, gf = A1[r] + bF, gg = A2[r] + bG, go = A3[r] + bO;
        const float ii = 1.f / (1.f + __expf(-gi));
        const float ff = 1.f / (1.f + __expf(-gf));
        const float gv = tanhf(gg);
        const float oo = 1.f / (1.f + __expf(-go));
        cs[r] = ff * cs[r] + ii * gv;
        const float hv = oo * tanhf(cs[r]);
        const bf16_t hvb = (bf16_t)hv;
        __hip_atomic_store(hn + (size_t)r * 1024, __builtin_bit_cast(u16, hvb),
                           __ATOMIC_RELAXED, __HIP_MEMORY_SCOPE_AGENT);
      }
      asm volatile("s_waitcnt vmcnt(0)" ::: "memory");  // only wave0 stores h
      if (lane == 0)
        __hip_atomic_store(flg + colg, (u32)(t + 1), __ATOMIC_RELAXED,
                           __HIP_MEMORY_SCOPE_AGENT);
    }
  }

  // ---- final FC + sigmoid: colg 0 WG of each clique handles its 16 batches ----
  if (colg != 0) return;
  if (w == 0) {
    u32 v = __hip_atomic_load(flg + lane, __ATOMIC_RELAXED, __HIP_MEMORY_SCOPE_AGENT);
    while (!__all(v >= (u32)T_SEQ)) {
      __builtin_amdgcn_s_sleep(1);
      v = __hip_atomic_load(flg + lane, __ATOMIC_RELAXED, __HIP_MEMORY_SCOPE_AGENT);
    }
  }
  __syncthreads();
  if (tid < 64) {
    const int bth = tid >> 2, part = tid & 3;          // 16 batches x 4 parts
    const int gb = clq * 16 + bth;
    const u64* hp = (const u64*)(hb + (size_t)gb * 1024 + part * 256);  // hb[0] = final
    const float* wp = wfc + part * 256;
    float s = 0.f;
    for (int i = 0; i < 64; ++i) {
      union { u64 u; bf16_t h[4]; } xv;
      xv.u = ldA8(hp + i);
      s += (float)xv.h[0] * wp[i * 4] + (float)xv.h[1] * wp[i * 4 + 1] +
           (float)xv.h[2] * wp[i * 4 + 2] + (float)xv.h[3] * wp[i * 4 + 3];
    }
    s += __shfl_xor(s, 1);
    s += __shfl_xor(s, 2);
    if (part == 0) out[gb] = 1.f / (1.f + __expf(-(s + bfc[0])));
  }
}

extern "C" void kernel_launch(void* const* d_in, const int* in_sizes, int n_in,
                              void* d_out, int out_size, void* d_ws, size_t ws_size,
                              hipStream_t stream) {
  const int* x = (const int*)d_in[0];
  const float* emb = (const float*)d_in[1];
  const float* wih = (const float*)d_in[2];
  const float* whh = (const float*)d_in[3];
  const float* bih = (const float*)d_in[4];
  const float* bhh = (const float*)d_in[5];
  const float* wfc = (const float*)d_in[6];
  const float* bfc = (const float*)d_in[7];
  float* out = (float*)d_out;

  char* ws = (char*)d_ws;
  bf16_t* xe = (bf16_t*)ws;                                    // 33,554,432 B
  bf16_t* wihb = (bf16_t*)(ws + 33554432);                     //  4,194,304 B
  bf16_t* hb = (bf16_t*)(ws + 33554432 + 4194304);             //  8,388,608 B
  u32* flags = (u32*)(ws + 33554432 + 4194304 + 8388608);      //      1,024 B

  hipMemsetAsync(hb, 0, 131072, stream);                       // h buffer 0 = 0
  hipMemsetAsync(flags, 0, 1024, stream);                      // all clique flags = 0
  gather_xe<<<32768, 64, 0, stream>>>(x, emb, xe);
  cvt_f32_bf16<<<1024, 256, 0, stream>>>(wih, wihb, 262144);

  void* args[] = {(void*)&xe, (void*)&wihb, (void*)&whh, (void*)&bih, (void*)&bhh,
                  (void*)&wfc, (void*)&bfc, (void*)&hb, (void*)&flags, (void*)&out};
  hipLaunchCooperativeKernel((const void*)lstm_seq, dim3(256), dim3(512), args, 0, stream);
}